// Round 1
// baseline (780.519 us; speedup 1.0000x reference)
//
#include <hip/hip_runtime.h>
#include <hip/hip_bf16.h>
#include <cstdint>

#define VOCAB 100000
#define EMB 300
#define H1D 100
#define H2D 100
#define PRODD 100
#define NE 301        // 300 emb dims + 1 bias row (evoke_b)
#define KP 128        // padded h
#define NP 128        // padded p
#define BM 64         // batch rows per block
#define BTOT 16384

typedef __attribute__((ext_vector_type(8))) short short8;
typedef __attribute__((ext_vector_type(4))) float f32x4;

__device__ __forceinline__ unsigned short f2bf(float f) {
    uint32_t u = __float_as_uint(f);
    uint32_t r = (u + 0x7fffu + ((u >> 16) & 1u)) >> 16;   // RNE
    return (unsigned short)r;
}

// ---------------------------------------------------------------------------
// Prep 1: pack evoke_k (+ evoke_b as row e=300) into bf16, padded [NE][128p][128h],
// with 16B-group XOR swizzle along h-chunks: group (p,c') holds h-chunk c = c'^(p&7).
// ---------------------------------------------------------------------------
__global__ __launch_bounds__(256) void k_ekprep(const float* __restrict__ evoke_k,
                                                const float* __restrict__ evoke_b,
                                                unsigned short* __restrict__ ekp) {
    int e = blockIdx.x;            // 0..300
    int tid = threadIdx.x;
    for (int i = 0; i < 8; ++i) {
        int g  = i * 256 + tid;    // 0..2047
        int p  = g >> 4;           // 0..127
        int cp = g & 15;           // stored chunk index c'
        int c  = cp ^ (p & 7);     // source h-chunk
        int h0 = c * 8;
        float vals[8];
#pragma unroll
        for (int j = 0; j < 8; ++j) {
            int h = h0 + j;
            float vv = 0.f;
            if (p < PRODD && h < H2D) {
                vv = (e < EMB) ? evoke_k[(size_t)e * 10000 + p * 100 + h]
                               : evoke_b[p * 100 + h];
            }
            vals[j] = vv;
        }
        uint32_t outd[4];
#pragma unroll
        for (int k = 0; k < 4; ++k) {
            outd[k] = (uint32_t)f2bf(vals[2 * k]) | ((uint32_t)f2bf(vals[2 * k + 1]) << 16);
        }
        uint4* dst = (uint4*)((uint32_t*)ekp + (size_t)e * 8192 + p * 64 + cp * 4);
        *dst = make_uint4(outd[0], outd[1], outd[2], outd[3]);
    }
}

// ---------------------------------------------------------------------------
// Prep 2: time MLP -> tv, stored bf16 [B][128] (h padded with zeros)
// ---------------------------------------------------------------------------
__global__ __launch_bounds__(256) void k_tv(const float* __restrict__ times,
                                            const float* __restrict__ h1_k,
                                            const float* __restrict__ h1_b,
                                            const float* __restrict__ h2_k,
                                            const float* __restrict__ h2_b,
                                            unsigned short* __restrict__ tvp) {
    __shared__ float h1s[16][100];
    int b0 = blockIdx.x * 16;
    for (int idx = threadIdx.x; idx < 1600; idx += 256) {
        int bb = idx / 100, i = idx - bb * 100;
        h1s[bb][i] = tanhf(times[b0 + bb] * h1_k[i] + h1_b[i]);
    }
    __syncthreads();
    for (int idx = threadIdx.x; idx < 1600; idx += 256) {
        int bb = idx / 100, j = idx - bb * 100;
        float acc = h2_b[j];
        for (int i = 0; i < 100; ++i) acc += h1s[bb][i] * h2_k[i * 100 + j];
        tvp[(size_t)(b0 + bb) * KP + j] = f2bf(tanhf(acc));
    }
    for (int idx = threadIdx.x; idx < 16 * 28; idx += 256) {
        int bb = idx / 28, j = 100 + (idx - bb * 28);
        tvp[(size_t)(b0 + bb) * KP + j] = 0;
    }
}

// ---------------------------------------------------------------------------
// Prep 3: G = last_k last_k^T (padded 128x128), v = last_k last_b, c0 = |last_b|^2.
// Also zeroes d_out (runs before main kernel's atomics).
// ---------------------------------------------------------------------------
__global__ __launch_bounds__(128) void k_gprep(const float* __restrict__ last_k,
                                               const float* __restrict__ last_b,
                                               float* __restrict__ G,
                                               float* __restrict__ vvec,
                                               float* __restrict__ c0,
                                               float* __restrict__ out) {
    int p = blockIdx.x;   // 0..127
    int q = threadIdx.x;  // 0..127
    __shared__ float row[EMB];
    for (int d = q; d < EMB; d += 128) row[d] = (p < PRODD) ? last_k[p * EMB + d] : 0.f;
    __syncthreads();
    float acc = 0.f;
    if (p < PRODD && q < PRODD) {
        for (int d = 0; d < EMB; ++d) acc += row[d] * last_k[q * EMB + d];
    }
    G[p * NP + q] = acc;
    if (q == 0) {
        float a = 0.f;
        if (p < PRODD) {
            for (int d = 0; d < EMB; ++d) a += row[d] * last_b[d];
        }
        vvec[p] = a;
        if (p == 0) {
            float s = 0.f;
            for (int d = 0; d < EMB; ++d) s += last_b[d] * last_b[d];
            *c0 = s;
            *out = 0.f;
        }
    }
}

// ---------------------------------------------------------------------------
// Main: per block 64 batch rows x 128 (padded) p.
// e-loop: S_e[b,p] = sum_h tv[b,h]*EK[e,p,h] via MFMA (tv stationary A-frags in regs,
// EKe streamed to LDS); fold S_e into acc_t/acc_c with per-row emb scalars.
// Epilogue: logit = mvt^T G mvc + v^T(mvt+mvc) + c0; BCE; block-reduce; atomicAdd.
// ---------------------------------------------------------------------------
__global__ __launch_bounds__(256) void k_main(
    const int* __restrict__ targets, const int* __restrict__ contexts,
    const float* __restrict__ labels,
    const float* __restrict__ targetemb, const float* __restrict__ contextemb,
    const unsigned short* __restrict__ ekp, const unsigned short* __restrict__ tvp,
    const float* __restrict__ G, const float* __restrict__ vvec,
    const float* __restrict__ c0p, float* __restrict__ out) {
    extern __shared__ char smem[];
    // main loop: EKe bf16 [0, 32768); emb fp32 [32768, 49152)
    // epilogue : mv_t [0, 28672); mv_c [28672, 57344)   (stride 112 floats/row)
    __shared__ float bsum[4];

    const int tid  = threadIdx.x;
    const int lane = tid & 63;
    const int w    = tid >> 6;       // wave 0..3
    const int l15  = lane & 15;
    const int l4   = lane >> 4;      // 0..3
    const int n0   = w * 32;         // wave p-base
    const int m0   = blockIdx.x * BM;

    // stationary tv A-frags (bf16): [mt][ks], m = l15, k-chunk = l4*8
    short8 afrag[4][4];
#pragma unroll
    for (int mt = 0; mt < 4; ++mt) {
        int bg = m0 + mt * 16 + l15;
#pragma unroll
        for (int ks = 0; ks < 4; ++ks) {
            afrag[mt][ks] = *(const short8*)(tvp + (size_t)bg * KP + ks * 32 + l4 * 8);
        }
    }

    // precomputed LDS byte offsets for B-frags (swizzle-aware)
    int boff[2][4];
#pragma unroll
    for (int nt = 0; nt < 2; ++nt) {
        int p = n0 + nt * 16 + l15;
#pragma unroll
        for (int ks = 0; ks < 4; ++ks) {
            int c = ks * 4 + l4;
            boff[nt][ks] = p * 256 + ((c ^ (p & 7)) << 4);
        }
    }

    f32x4 acc_t[4][2], acc_c[4][2];
    const f32x4 zf = {0.f, 0.f, 0.f, 0.f};
#pragma unroll
    for (int mt = 0; mt < 4; ++mt) {
#pragma unroll
        for (int nt = 0; nt < 2; ++nt) { acc_t[mt][nt] = zf; acc_c[mt][nt] = zf; }
    }

    for (int e = 0; e < NE; ++e) {
        __syncthreads();   // previous iteration's LDS reads complete
        // stage EKe (32KB) global -> LDS, 16B per lane per issue
        {
            const char* gsrc = (const char*)(ekp + (size_t)e * (NP * KP));
#pragma unroll
            for (int i = 0; i < 8; ++i) {
                int off = i * 4096 + tid * 16;
                __builtin_amdgcn_global_load_lds(
                    (__attribute__((address_space(1))) void*)(gsrc + off),
                    (__attribute__((address_space(3))) void*)(smem + off),
                    16, 0, 0);
            }
        }
        if ((e & 31) == 0) {  // stage emb chunk [e, e+32) as [es][64] fp32, both branches
            float* embl = (float*)(smem + 32768);
            int b_loc2 = tid >> 2;
            int grp = tid & 3;
            int bg = m0 + b_loc2;
            const float* tb = targetemb + (size_t)targets[bg] * EMB;
            const float* cb = contextemb + (size_t)contexts[bg] * EMB;
#pragma unroll
            for (int half = 0; half < 2; ++half) {
                int es0 = grp * 8 + half * 4;
                int eg = e + es0;
                float vt[4], vc[4];
                if (eg + 3 < EMB) {
                    float4 ft = *(const float4*)(tb + eg);
                    float4 fc = *(const float4*)(cb + eg);
                    vt[0] = ft.x; vt[1] = ft.y; vt[2] = ft.z; vt[3] = ft.w;
                    vc[0] = fc.x; vc[1] = fc.y; vc[2] = fc.z; vc[3] = fc.w;
                } else {
#pragma unroll
                    for (int j = 0; j < 4; ++j) {
                        int ee = eg + j;
                        float a = 0.f, b2 = 0.f;
                        if (ee < EMB)      { a = tb[ee]; b2 = cb[ee]; }
                        else if (ee == EMB){ a = 1.f;    b2 = 1.f;    }  // bias row
                        vt[j] = a; vc[j] = b2;
                    }
                }
#pragma unroll
                for (int j = 0; j < 4; ++j) {
                    embl[(es0 + j) * 64 + b_loc2]        = vt[j];
                    embl[2048 + (es0 + j) * 64 + b_loc2] = vc[j];
                }
            }
        }
        __syncthreads();   // LDS staged (drains vmcnt for global_load_lds)

        // S_e via MFMA
        f32x4 S[4][2];
#pragma unroll
        for (int mt = 0; mt < 4; ++mt) { S[mt][0] = zf; S[mt][1] = zf; }
#pragma unroll
        for (int ks = 0; ks < 4; ++ks) {
            short8 bf0 = *(const short8*)(smem + boff[0][ks]);
            short8 bf1 = *(const short8*)(smem + boff[1][ks]);
#pragma unroll
            for (int mt = 0; mt < 4; ++mt) {
                S[mt][0] = __builtin_amdgcn_mfma_f32_16x16x32_bf16(afrag[mt][ks], bf0, S[mt][0], 0, 0, 0);
                S[mt][1] = __builtin_amdgcn_mfma_f32_16x16x32_bf16(afrag[mt][ks], bf1, S[mt][1], 0, 0, 0);
            }
        }
        // fold with emb scalars (C-layout rows: mt*16 + l4*4 + r)
        const float* embl = (const float*)(smem + 32768);
        int esub = e & 31;
#pragma unroll
        for (int mt = 0; mt < 4; ++mt) {
            int row0 = mt * 16 + l4 * 4;
            float4 et = *(const float4*)(embl + esub * 64 + row0);
            float4 ec = *(const float4*)(embl + 2048 + esub * 64 + row0);
#pragma unroll
            for (int nt = 0; nt < 2; ++nt) {
                acc_t[mt][nt][0] += et.x * S[mt][nt][0];
                acc_t[mt][nt][1] += et.y * S[mt][nt][1];
                acc_t[mt][nt][2] += et.z * S[mt][nt][2];
                acc_t[mt][nt][3] += et.w * S[mt][nt][3];
                acc_c[mt][nt][0] += ec.x * S[mt][nt][0];
                acc_c[mt][nt][1] += ec.y * S[mt][nt][1];
                acc_c[mt][nt][2] += ec.z * S[mt][nt][2];
                acc_c[mt][nt][3] += ec.w * S[mt][nt][3];
            }
        }
    }

    // ---- epilogue ----
    __syncthreads();
    float* mvt = (float*)smem;              // [64][112]
    float* mvc = (float*)(smem + 28672);    // [64][112]
#pragma unroll
    for (int mt = 0; mt < 4; ++mt) {
#pragma unroll
        for (int nt = 0; nt < 2; ++nt) {
            int col = n0 + nt * 16 + l15;
            if (col < 112) {
#pragma unroll
                for (int r = 0; r < 4; ++r) {
                    int row = mt * 16 + l4 * 4 + r;
                    mvt[row * 112 + col] = acc_t[mt][nt][r];
                    mvc[row * 112 + col] = acc_c[mt][nt][r];
                }
            }
        }
    }
    __syncthreads();

    int b_loc = tid >> 2;
    int quar  = tid & 3;
    // cache mv_c row in registers
    float4 cr[28];
#pragma unroll
    for (int i = 0; i < 28; ++i) cr[i] = *(const float4*)(mvc + b_loc * 112 + i * 4);

    float part = 0.f;
    for (int pp = 0; pp < 28; ++pp) {
        int p = quar * 28 + pp;
        const float4* Grow = (const float4*)(G + p * NP);
        float wq = 0.f;
#pragma unroll 7
        for (int qq = 0; qq < 28; ++qq) {
            float4 g = Grow[qq];
            float4 m = cr[qq];
            wq += g.x * m.x + g.y * m.y + g.z * m.z + g.w * m.w;
        }
        float mtv = mvt[b_loc * 112 + p];
        float mcv = mvc[b_loc * 112 + p];
        part += mtv * wq + vvec[p] * (mtv + mcv);
    }
    // sum the 4 p-quarters of each b (threads 4b..4b+3 are adjacent lanes)
    part += __shfl_xor(part, 1);
    part += __shfl_xor(part, 2);

    float lossv = 0.f;
    if (quar == 0) {
        float logit = part + *c0p;
        float lab = labels[m0 + b_loc];
        lossv = fmaxf(logit, 0.f) - logit * lab + log1pf(expf(-fabsf(logit)));
    }
#pragma unroll
    for (int off = 4; off < 64; off <<= 1) lossv += __shfl_xor(lossv, off);
    if (lane == 0) bsum[w] = lossv;
    __syncthreads();
    if (tid == 0) {
        atomicAdd(out, (bsum[0] + bsum[1] + bsum[2] + bsum[3]) * (1.0f / 16384.0f));
    }
}

// ---------------------------------------------------------------------------
extern "C" void kernel_launch(void* const* d_in, const int* in_sizes, int n_in,
                              void* d_out, int out_size, void* d_ws, size_t ws_size,
                              hipStream_t stream) {
    const int*   targets    = (const int*)d_in[0];
    const int*   contexts   = (const int*)d_in[1];
    const float* times      = (const float*)d_in[2];
    const float* labels     = (const float*)d_in[3];
    const float* targetemb  = (const float*)d_in[4];
    const float* contextemb = (const float*)d_in[5];
    const float* h1_k       = (const float*)d_in[6];
    const float* h1_b       = (const float*)d_in[7];
    const float* h2_k       = (const float*)d_in[8];
    const float* h2_b       = (const float*)d_in[9];
    const float* evoke_k    = (const float*)d_in[10];
    const float* evoke_b    = (const float*)d_in[11];
    const float* last_k     = (const float*)d_in[12];
    const float* last_b     = (const float*)d_in[13];
    float* out = (float*)d_out;

    char* ws = (char*)d_ws;
    unsigned short* ekp = (unsigned short*)ws;                         // 301*128*128*2 = 9,863,168
    unsigned short* tvp = (unsigned short*)(ws + 9863168);             // 16384*128*2   = 4,194,304
    float* G   = (float*)(ws + 9863168 + 4194304);                     // 128*128*4     = 65,536
    float* vv  = (float*)(ws + 9863168 + 4194304 + 65536);             // 128*4         = 512
    float* c0  = (float*)(ws + 9863168 + 4194304 + 65536 + 512);       // 4

    k_ekprep<<<dim3(NE), dim3(256), 0, stream>>>(evoke_k, evoke_b, ekp);
    k_tv<<<dim3(BTOT / 16), dim3(256), 0, stream>>>(times, h1_k, h1_b, h2_k, h2_b, tvp);
    k_gprep<<<dim3(NP), dim3(128), 0, stream>>>(last_k, last_b, G, vv, c0, out);
    k_main<<<dim3(BTOT / BM), dim3(256), 57344, stream>>>(
        targets, contexts, labels, targetemb, contextemb, ekp, tvp, G, vv, c0, out);
}

// Round 2
// 722.635 us; speedup vs baseline: 1.0801x; 1.0801x over previous
//
#include <hip/hip_runtime.h>
#include <cstdint>

#define VOCAB 100000
#define EMB 300
#define NE 301         // 300 emb dims + 1 bias row (evoke_b)
#define KP 128         // padded h (bf16 elements per p-row)
#define PSTORE 112     // stored p rows per e (7 tiles of 16; p>=100 zero-padded)
#define EKSTRIDE 28672 // bytes per e slab = 112*128*2
#define NP 128         // G row stride (floats)
#define BM 64
#define BTOT 16384

typedef __attribute__((ext_vector_type(8))) short short8;
typedef __attribute__((ext_vector_type(4))) float f32x4;

__device__ __forceinline__ unsigned short f2bf(float f) {
    uint32_t u = __float_as_uint(f);
    uint32_t r = (u + 0x7fffu + ((u >> 16) & 1u)) >> 16;   // RNE
    return (unsigned short)r;
}

// ---------------------------------------------------------------------------
// Prep 1: pack evoke_k (+ evoke_b as e=300) into bf16 [NE][112 p][128 h], no swizzle.
// 7168 dwords per e; fully coalesced writes, float2 vector reads.
// ---------------------------------------------------------------------------
__global__ __launch_bounds__(256) void k_ekprep(const float* __restrict__ evoke_k,
                                                const float* __restrict__ evoke_b,
                                                unsigned short* __restrict__ ekp) {
    int e = blockIdx.x;            // 0..300
    int tid = threadIdx.x;
    const float* src = (e < EMB) ? (evoke_k + (size_t)e * 10000) : evoke_b;
    uint32_t* dst = (uint32_t*)ekp + (size_t)e * (EKSTRIDE / 4);
#pragma unroll
    for (int i = 0; i < 28; ++i) {
        int d = i * 256 + tid;     // 0..7167
        int p = d >> 6;            // 0..111
        int h2 = d & 63;           // dword within row (h = 2*h2, 2*h2+1)
        uint32_t val = 0;
        if (p < 100 && h2 < 50) {
            float2 s = *(const float2*)(src + p * 100 + 2 * h2);
            val = (uint32_t)f2bf(s.x) | ((uint32_t)f2bf(s.y) << 16);
        }
        dst[d] = val;
    }
}

// ---------------------------------------------------------------------------
// Prep 2: time MLP -> tv, stored bf16 [B][128] (h padded with zeros)
// ---------------------------------------------------------------------------
__global__ __launch_bounds__(256) void k_tv(const float* __restrict__ times,
                                            const float* __restrict__ h1_k,
                                            const float* __restrict__ h1_b,
                                            const float* __restrict__ h2_k,
                                            const float* __restrict__ h2_b,
                                            unsigned short* __restrict__ tvp) {
    __shared__ float h1s[16][100];
    int b0 = blockIdx.x * 16;
    for (int idx = threadIdx.x; idx < 1600; idx += 256) {
        int bb = idx / 100, i = idx - bb * 100;
        h1s[bb][i] = tanhf(times[b0 + bb] * h1_k[i] + h1_b[i]);
    }
    __syncthreads();
    for (int idx = threadIdx.x; idx < 1600; idx += 256) {
        int bb = idx / 100, j = idx - bb * 100;
        float acc = h2_b[j];
        for (int i = 0; i < 100; ++i) acc += h1s[bb][i] * h2_k[i * 100 + j];
        tvp[(size_t)(b0 + bb) * KP + j] = f2bf(tanhf(acc));
    }
    for (int idx = threadIdx.x; idx < 16 * 28; idx += 256) {
        int bb = idx / 28, j = 100 + (idx - bb * 28);
        tvp[(size_t)(b0 + bb) * KP + j] = 0;
    }
}

// ---------------------------------------------------------------------------
// Prep 3: G = last_k last_k^T (padded 128x128), v = last_k last_b, c0 = |last_b|^2.
// Also zeroes d_out (runs before main kernel's atomics).
// ---------------------------------------------------------------------------
__global__ __launch_bounds__(128) void k_gprep(const float* __restrict__ last_k,
                                               const float* __restrict__ last_b,
                                               float* __restrict__ G,
                                               float* __restrict__ vvec,
                                               float* __restrict__ c0,
                                               float* __restrict__ out) {
    int p = blockIdx.x;   // 0..127
    int q = threadIdx.x;  // 0..127
    __shared__ float row[EMB];
    for (int d = q; d < EMB; d += 128) row[d] = (p < 100) ? last_k[p * EMB + d] : 0.f;
    __syncthreads();
    float acc = 0.f;
    if (p < 100 && q < 100) {
        for (int d = 0; d < EMB; ++d) acc += row[d] * last_k[q * EMB + d];
    }
    G[p * NP + q] = acc;
    if (q == 0) {
        float a = 0.f;
        if (p < 100) {
            for (int d = 0; d < EMB; ++d) a += row[d] * last_b[d];
        }
        vvec[p] = a;
        if (p == 0) {
            float s = 0.f;
            for (int d = 0; d < EMB; ++d) s += last_b[d] * last_b[d];
            *c0 = s;
            *out = 0.f;
        }
    }
}

// ---------------------------------------------------------------------------
// Main: 64 batch rows x 112 p per block; EK B-frags loaded global->VGPR directly
// (per-wave-private p range), 2-deep pipelined, NO per-iteration barriers.
// emb scalars staged as bf16 in LDS in 2 chunks (2 barriers total in the e-loop).
// ---------------------------------------------------------------------------
__global__ __launch_bounds__(256, 1) void k_main(
    const int* __restrict__ targets, const int* __restrict__ contexts,
    const float* __restrict__ labels,
    const float* __restrict__ targetemb, const float* __restrict__ contextemb,
    const unsigned short* __restrict__ ekp, const unsigned short* __restrict__ tvp,
    const float* __restrict__ G, const float* __restrict__ vvec,
    const float* __restrict__ c0p, float* __restrict__ out) {
    extern __shared__ char smem[];
    // loop phase  : embl bf16 [152 e][2 br][64 b] = 38,912 B at smem+0
    // epilogue    : mv_t [64][112] at 0, mv_c at +28672  (57,344 B total)
    __shared__ float bsum[4];

    const int tid  = threadIdx.x;
    const int lane = tid & 63;
    const int w    = tid >> 6;       // wave 0..3
    const int l15  = lane & 15;
    const int l4   = lane >> 4;      // 0..3
    const int m0   = blockIdx.x * BM;

    unsigned short* embl = (unsigned short*)smem;

    // ---- stationary tv A-frags (bf16): m = l15, k-chunk = ks*32 + l4*8 ----
    short8 afrag[4][4];
#pragma unroll
    for (int mt = 0; mt < 4; ++mt) {
        int bg = m0 + mt * 16 + l15;
#pragma unroll
        for (int ks = 0; ks < 4; ++ks) {
            afrag[mt][ks] = *(const short8*)(tvp + (size_t)bg * KP + ks * 32 + l4 * 8);
        }
    }

    // ---- per-wave B-frag activity + global byte offsets within an e-slab ----
    bool act[2];
    int  loff[2][4];
#pragma unroll
    for (int nt = 0; nt < 2; ++nt) {
        int t = w * 2 + nt;          // n-tile 0..7; tile 7 doesn't exist (p<112)
        act[nt] = (t < 7);
        int p = t * 16 + l15;
#pragma unroll
        for (int ks = 0; ks < 4; ++ks) {
            loff[nt][ks] = (t < 7) ? (p * 256 + ks * 64 + l4 * 16) : 0;
        }
    }

    // ---- emb staging (bf16) for chunk c: e in [152c, 152c+152) (c=1 incl bias 300) ----
    auto stage_emb = [&](int c) {
        int b = tid & 63;
        int branch = (tid >> 6) & 1;
        int seg = tid >> 7;
        int ebase = c * 152;
        int nreal = (c == 0) ? 152 : 148;   // real e count in chunk
        int half = (nreal + 1) / 2;
        int s0 = seg * half;
        int s1 = (s0 + half < nreal) ? (s0 + half) : nreal;
        const int* idxp = branch ? contexts : targets;
        const float* base = branch ? contextemb : targetemb;
        const float* row = base + (size_t)idxp[m0 + b] * EMB + ebase;
        int off = branch * 64 + b;
        int e = s0;
        for (; e + 3 < s1; e += 4) {
            float4 v = *(const float4*)(row + e);
            embl[(e + 0) * 128 + off] = f2bf(v.x);
            embl[(e + 1) * 128 + off] = f2bf(v.y);
            embl[(e + 2) * 128 + off] = f2bf(v.z);
            embl[(e + 3) * 128 + off] = f2bf(v.w);
        }
        for (; e < s1; ++e) embl[e * 128 + off] = f2bf(row[e]);
        if (c == 1 && seg == 1) embl[148 * 128 + off] = 0x3F80;   // bias row e=300 -> 1.0
    };

    f32x4 acc_t[4][2], acc_c[4][2];
    const f32x4 zf = {0.f, 0.f, 0.f, 0.f};
#pragma unroll
    for (int mt = 0; mt < 4; ++mt) {
#pragma unroll
        for (int nt = 0; nt < 2; ++nt) { acc_t[mt][nt] = zf; acc_c[mt][nt] = zf; }
    }

    auto loadbuf = [&](short8 (&buf)[2][4], int ei) {
        const char* sp = (const char*)ekp + (size_t)ei * EKSTRIDE;
#pragma unroll
        for (int nt = 0; nt < 2; ++nt) {
            if (act[nt]) {
#pragma unroll
                for (int ks = 0; ks < 4; ++ks) {
                    buf[nt][ks] = *(const short8*)(sp + loff[nt][ks]);
                }
            }
        }
    };

    auto compute = [&](int el, short8 (&buf)[2][4]) {
        // emb scalars for this e (broadcast LDS reads, bf16 -> fp32 unpack)
        float et[4][4], ec[4][4];
#pragma unroll
        for (int mt = 0; mt < 4; ++mt) {
            int row0 = mt * 16 + l4 * 4;
            uint2 dt = *(const uint2*)(embl + el * 128 + row0);
            uint2 dc = *(const uint2*)(embl + el * 128 + 64 + row0);
            et[mt][0] = __uint_as_float(dt.x << 16);
            et[mt][1] = __uint_as_float(dt.x & 0xffff0000u);
            et[mt][2] = __uint_as_float(dt.y << 16);
            et[mt][3] = __uint_as_float(dt.y & 0xffff0000u);
            ec[mt][0] = __uint_as_float(dc.x << 16);
            ec[mt][1] = __uint_as_float(dc.x & 0xffff0000u);
            ec[mt][2] = __uint_as_float(dc.y << 16);
            ec[mt][3] = __uint_as_float(dc.y & 0xffff0000u);
        }
#pragma unroll
        for (int nt = 0; nt < 2; ++nt) {
            if (act[nt]) {
                f32x4 S[4];
#pragma unroll
                for (int mt = 0; mt < 4; ++mt) S[mt] = zf;
#pragma unroll
                for (int ks = 0; ks < 4; ++ks) {
#pragma unroll
                    for (int mt = 0; mt < 4; ++mt) {
                        S[mt] = __builtin_amdgcn_mfma_f32_16x16x32_bf16(
                            afrag[mt][ks], buf[nt][ks], S[mt], 0, 0, 0);
                    }
                }
#pragma unroll
                for (int mt = 0; mt < 4; ++mt) {
#pragma unroll
                    for (int r = 0; r < 4; ++r) {
                        acc_t[mt][nt][r] += et[mt][r] * S[mt][r];
                        acc_c[mt][nt][r] += ec[mt][r] * S[mt][r];
                    }
                }
            }
        }
    };

    // ---- one-shot stage of chunk 0, single barrier ----
    stage_emb(0);
    __syncthreads();

    // ---- barrier-free 2-deep pipelined e-loop ----
    short8 bufA[2][4], bufB[2][4];
    loadbuf(bufA, 0);
#pragma unroll 1
    for (int ee = 0; ee < 150; ++ee) {
        if (ee == 76) {                  // e switches into [152, 301) range
            __syncthreads();
            stage_emb(1);
            __syncthreads();
        }
        int e0 = 2 * ee;
        int elb = (ee >= 76) ? 152 : 0;
        loadbuf(bufB, e0 + 1);
        compute(e0 - elb, bufA);
        int e2 = (e0 + 2 < NE) ? (e0 + 2) : (NE - 1);
        loadbuf(bufA, e2);
        compute(e0 + 1 - elb, bufB);
    }
    compute(300 - 152, bufA);            // e = 300 (bias row)

    // ---- epilogue ----
    __syncthreads();
    float* mvt = (float*)smem;              // [64][112]
    float* mvc = (float*)(smem + 28672);    // [64][112]
#pragma unroll
    for (int mt = 0; mt < 4; ++mt) {
#pragma unroll
        for (int nt = 0; nt < 2; ++nt) {
            if (act[nt]) {
                int col = (w * 2 + nt) * 16 + l15;   // 0..111
#pragma unroll
                for (int r = 0; r < 4; ++r) {
                    int row = mt * 16 + l4 * 4 + r;
                    mvt[row * 112 + col] = acc_t[mt][nt][r];
                    mvc[row * 112 + col] = acc_c[mt][nt][r];
                }
            }
        }
    }
    __syncthreads();

    int b_loc = tid >> 2;
    int quar  = tid & 3;
    float4 cr[28];
#pragma unroll
    for (int i = 0; i < 28; ++i) cr[i] = *(const float4*)(mvc + b_loc * 112 + i * 4);

    float part = 0.f;
    for (int pp = 0; pp < 28; ++pp) {
        int p = quar * 28 + pp;
        const float4* Grow = (const float4*)(G + p * NP);
        float wq = 0.f;
#pragma unroll 7
        for (int qq = 0; qq < 28; ++qq) {
            float4 g = Grow[qq];
            float4 m = cr[qq];
            wq += g.x * m.x + g.y * m.y + g.z * m.z + g.w * m.w;
        }
        float mtv = mvt[b_loc * 112 + p];
        float mcv = mvc[b_loc * 112 + p];
        part += mtv * wq + vvec[p] * (mtv + mcv);
    }
    part += __shfl_xor(part, 1);
    part += __shfl_xor(part, 2);

    float lossv = 0.f;
    if (quar == 0) {
        float logit = part + *c0p;
        float lab = labels[m0 + b_loc];
        lossv = fmaxf(logit, 0.f) - logit * lab + log1pf(expf(-fabsf(logit)));
    }
#pragma unroll
    for (int off = 4; off < 64; off <<= 1) lossv += __shfl_xor(lossv, off);
    if (lane == 0) bsum[w] = lossv;
    __syncthreads();
    if (tid == 0) {
        atomicAdd(out, (bsum[0] + bsum[1] + bsum[2] + bsum[3]) * (1.0f / 16384.0f));
    }
}

// ---------------------------------------------------------------------------
extern "C" void kernel_launch(void* const* d_in, const int* in_sizes, int n_in,
                              void* d_out, int out_size, void* d_ws, size_t ws_size,
                              hipStream_t stream) {
    const int*   targets    = (const int*)d_in[0];
    const int*   contexts   = (const int*)d_in[1];
    const float* times      = (const float*)d_in[2];
    const float* labels     = (const float*)d_in[3];
    const float* targetemb  = (const float*)d_in[4];
    const float* contextemb = (const float*)d_in[5];
    const float* h1_k       = (const float*)d_in[6];
    const float* h1_b       = (const float*)d_in[7];
    const float* h2_k       = (const float*)d_in[8];
    const float* h2_b       = (const float*)d_in[9];
    const float* evoke_k    = (const float*)d_in[10];
    const float* evoke_b    = (const float*)d_in[11];
    const float* last_k     = (const float*)d_in[12];
    const float* last_b     = (const float*)d_in[13];
    float* out = (float*)d_out;

    char* ws = (char*)d_ws;
    unsigned short* ekp = (unsigned short*)ws;                 // 301*112*128*2 = 8,630,272
    unsigned short* tvp = (unsigned short*)(ws + 8630272);     // 16384*128*2   = 4,194,304
    float* G   = (float*)(ws + 8630272 + 4194304);             // 128*128*4     = 65,536
    float* vv  = (float*)(ws + 8630272 + 4194304 + 65536);     // 128*4
    float* c0  = (float*)(ws + 8630272 + 4194304 + 65536 + 512);

    k_ekprep<<<dim3(NE), dim3(256), 0, stream>>>(evoke_k, evoke_b, ekp);
    k_tv<<<dim3(BTOT / 16), dim3(256), 0, stream>>>(times, h1_k, h1_b, h2_k, h2_b, tvp);
    k_gprep<<<dim3(NP), dim3(128), 0, stream>>>(last_k, last_b, G, vv, c0, out);
    k_main<<<dim3(BTOT / BM), dim3(256), 57344, stream>>>(
        targets, contexts, labels, targetemb, contextemb, ekp, tvp, G, vv, c0, out);
}